// Round 8
// baseline (1321.379 us; speedup 1.0000x reference)
//
#include <hip/hip_runtime.h>
#include <stdint.h>

// Problem constants
#define B_ 16
#define C_ 512
#define T_ 4000
#define TPAD 4096   // hT rows padded per batch so tail N-tiles read in-bounds

typedef float f32x4 __attribute__((ext_vector_type(4)));
typedef float f32x16 __attribute__((ext_vector_type(16)));
typedef __bf16 bf16x8 __attribute__((ext_vector_type(8)));

// ---------- helpers ----------
__device__ inline unsigned short f2b(float f) {   // fp32 -> bf16 bits, RNE
  uint32_t u = __builtin_bit_cast(uint32_t, f);
  u = (u + 0x7fffu + ((u >> 16) & 1u)) >> 16;
  return (unsigned short)u;
}
__device__ inline float b2f(unsigned short h) {
  uint32_t u = ((uint32_t)h) << 16;
  return __builtin_bit_cast(float, u);
}
__device__ inline void gl_lds16(const void* g, void* s) {
  __builtin_amdgcn_global_load_lds(
      (const __attribute__((address_space(1))) uint32_t*)g,
      (__attribute__((address_space(3))) uint32_t*)s, 16, 0, 0);
}

// ws float layout: [0..15] sum, [16..31] sumsq, [32..47] mean, [48..63] rstd,
//                  [64..575] s1[o], [576..1087] s2[o]
// byte 8192  : Wp bf16 [512][512]  (pw * gln_gamma, row-major o,c)
// byte 1<<20 : hT bf16 [16][4096][512]  (t-major, c contiguous)

__global__ void k_init(float* wsf) {
  int i = threadIdx.x;
  if (i < 32) wsf[i] = 0.f;
}

// one block per output row o: W'[o,c] = pw*gamma (bf16), s1[o]=sum W', s2[o]=sum pw*beta
__global__ __launch_bounds__(64) void k_prepw(const float* __restrict__ pw,
                                              const float* __restrict__ gamma,
                                              const float* __restrict__ beta,
                                              unsigned short* __restrict__ Wp,
                                              float* __restrict__ wsf) {
  int o = blockIdx.x, l = threadIdx.x;
  float a1 = 0.f, a2 = 0.f;
  for (int j = 0; j < 8; ++j) {
    int c = j * 64 + l;
    float wv = pw[o * 512 + c];
    unsigned short wb = f2b(wv * gamma[c]);
    Wp[o * 512 + c] = wb;
    a1 += b2f(wb);              // consistent with bf16 weights used in GEMM
    a2 += wv * beta[c];
  }
  for (int s = 32; s > 0; s >>= 1) { a1 += __shfl_down(a1, s); a2 += __shfl_down(a2, s); }
  if (l == 0) { wsf[64 + o] = a1; wsf[576 + o] = a2; }
}

// fused ReLU+BN+dwconv3+PReLU; writes hT[b][t][c] bf16 (transposed) + stats.
__global__ __launch_bounds__(512) void k_front(const float* __restrict__ x,
    const float* __restrict__ bng, const float* __restrict__ bnb,
    const float* __restrict__ bnm, const float* __restrict__ bnv,
    const float* __restrict__ dw, const float* __restrict__ pa,
    unsigned short* __restrict__ hT, float* __restrict__ wsf) {
  __shared__ unsigned short hs[256 * 128] __attribute__((aligned(16)));  // 64 KB
  __shared__ float psc[128], pbi[128], pq0[128], pq1[128], pq2[128];
  __shared__ float partial[16];
  int tid = threadIdx.x;
  int l = tid & 63, w = tid >> 6;
  int tb = blockIdx.x;   // 16 t-tiles of 256
  int cb = blockIdx.y;   // 4 c-chunks of 128
  int b  = blockIdx.z;
  int t0 = tb * 256;
  if (tid < 128) {
    int c = cb * 128 + tid;
    float sc = bng[c] * rsqrtf(bnv[c] + 1e-5f);
    psc[tid] = sc;
    pbi[tid] = bnb[c] - bnm[c] * sc;
    pq0[tid] = dw[3 * c];
    pq1[tid] = dw[3 * c + 1];
    pq2[tid] = dw[3 * c + 2];
  }
  float alpha = pa[0];
  __syncthreads();

  int t = t0 + 4 * l;
  bool full = (t + 3 < T_);          // lanes are either fully valid or fully out
  bool has_l = (t0 > 0);
  bool has_r = (t0 + 256 < T_);
  float sum = 0.f, sq = 0.f;
  int cs_x = (l & 7) << 3;           // swizzle term (t>>2 == l for all 4 outputs)

#pragma unroll 2
  for (int i = 0; i < 16; ++i) {
    int cl = w * 16 + i;
    const float* xr = x + ((size_t)b * C_ + cb * 128 + cl) * T_;
    float sc = psc[cl], bi = pbi[cl];
    float w0 = pq0[cl], w1 = pq1[cl], w2 = pq2[cl];
    f32x4 u;
    if (full) {
      const f32x4 v = *(const f32x4*)(xr + t);
      u.x = fmaxf(v.x, 0.f) * sc + bi;
      u.y = fmaxf(v.y, 0.f) * sc + bi;
      u.z = fmaxf(v.z, 0.f) * sc + bi;
      u.w = fmaxf(v.w, 0.f) * sc + bi;
    } else {
      u = (f32x4){0.f, 0.f, 0.f, 0.f};
    }
    float el = has_l ? (fmaxf(xr[t0 - 1], 0.f) * sc + bi) : 0.f;   // uniform addr
    float er = has_r ? (fmaxf(xr[t0 + 256], 0.f) * sc + bi) : 0.f; // uniform addr
    float up = __shfl_up(u.w, 1);   if (l == 0)  up = el;
    float un = __shfl_down(u.x, 1); if (l == 63) un = er;
    float h[4];
    h[0] = w0 * up  + w1 * u.x + w2 * u.y;
    h[1] = w0 * u.x + w1 * u.y + w2 * u.z;
    h[2] = w0 * u.y + w1 * u.z + w2 * u.w;
    h[3] = w0 * u.z + w1 * u.w + w2 * un;
    int cs = cl ^ cs_x;
#pragma unroll
    for (int j = 0; j < 4; ++j) {
      float p = h[j] >= 0.f ? h[j] : alpha * h[j];
      if (!full) p = 0.f;            // t >= 4000 rows stay exactly zero
      sum += p; sq += p * p;
      hs[(4 * l + j) * 128 + cs] = f2b(p);
    }
  }

  for (int s = 32; s > 0; s >>= 1) { sum += __shfl_down(sum, s); sq += __shfl_down(sq, s); }
  if (l == 0) { partial[w] = sum; partial[8 + w] = sq; }
  __syncthreads();
  if (tid == 0) {
    float a = 0.f, c2 = 0.f;
    for (int k = 0; k < 8; ++k) { a += partial[k]; c2 += partial[8 + k]; }
    atomicAdd(&wsf[b], a);
    atomicAdd(&wsf[16 + b], c2);
  }

  // LDS tile -> global hT[b][t0+tl][cb*128 + g*8], un-swizzled, 16B/thread/pass
  unsigned short* dstb = hT + ((size_t)b * TPAD + t0) * 512 + cb * 128;
#pragma unroll
  for (int p = 0; p < 8; ++p) {
    int idx = p * 512 + tid;
    int tl = idx >> 4, g = idx & 15;
    int gs = g ^ ((tl >> 2) & 7);
    uint4 val = *(const uint4*)(hs + tl * 128 + gs * 8);
    *(uint4*)(dstb + (size_t)tl * 512 + g * 8) = val;
  }
}

__global__ void k_finalize(float* wsf) {
  int b = threadIdx.x;
  if (b < 16) {
    float n = (float)C_ * (float)T_;
    float mean = wsf[b] / n;
    float var = wsf[16 + b] / n - mean * mean;
    wsf[32 + b] = mean;
    wsf[48 + b] = rsqrtf(fmaxf(var, 0.f) + 1e-8f);
  }
}

// GEMM v6: R3's 256x256 / BK=32 / counted-vmcnt structure, but 16 waves
// (1024 thr), per-wave 64x64 via mfma_32x32x16 -> acc 64 AGPR (vs 128),
// total regs ~134 -> target 32 resident waves/CU (2 blocks x 16 waves).
// Grid 512 blocks = one tail-free generation on 256 CUs.
__global__ __launch_bounds__(1024, 8) void k_gemm(const unsigned short* __restrict__ Wp,
    const unsigned short* __restrict__ hT, const float* __restrict__ x,
    const float* __restrict__ wsf, float* __restrict__ out) {
  __shared__ unsigned short As0[8192], As1[8192], Bs0[8192], Bs1[8192];  // 64 KB
  int tid = threadIdx.x;
  int l = tid & 63, w = tid >> 6;
  int nb = blockIdx.x, mb = blockIdx.y, b = blockIdx.z;
  int wm = w >> 2, wn = w & 3;       // 4 x 4 wave grid; per-wave 64 o x 64 t
  int lr = l & 31, lh = l >> 5;
  const unsigned short* hTb = hT + (size_t)b * TPAD * 512;

  // staging source offsets (element units), inverse-swizzled k-slot
  // 1024 threads cover one 256x32 panel: 16B-unit u = tid; row=u>>2, s=u&3
  int aoff, boff, ldso;
  {
    int row = tid >> 2, s = tid & 3;
    int ksl = (s ^ ((row >> 1) & 3)) << 3;
    aoff = (mb * 256 + row) * 512 + ksl;
    boff = (nb * 256 + row) * 512 + ksl;
    ldso = tid * 8;
  }

  // ds_read fragment offsets (element units); rows for 32x32 frags
  int aro[2][2], bro[2][2];          // [fm][ks], [fn][ks]
#pragma unroll
  for (int fm = 0; fm < 2; ++fm)
#pragma unroll
    for (int ks = 0; ks < 2; ++ks) {
      int row = wm * 64 + fm * 32 + lr;
      int slot = (ks * 2 + lh) ^ ((row >> 1) & 3);
      aro[fm][ks] = row * 32 + slot * 8;
    }
#pragma unroll
  for (int fn = 0; fn < 2; ++fn)
#pragma unroll
    for (int ks = 0; ks < 2; ++ks) {
      int row = wn * 64 + fn * 32 + lr;
      int slot = (ks * 2 + lh) ^ ((row >> 1) & 3);
      bro[fn][ks] = row * 32 + slot * 8;
    }

  // prologue: stage K-tile 0 -> buf0, K-tile 1 -> buf1; no drain
  gl_lds16(Wp + aoff, As0 + ldso);
  gl_lds16(hTb + boff, Bs0 + ldso);
  gl_lds16(Wp + aoff + 32, As1 + ldso);
  gl_lds16(hTb + boff + 32, Bs1 + ldso);

  unsigned short *cA = As0, *cB = Bs0;
  unsigned short *oA = As1, *oB = Bs1;

  f32x16 acc[2][2] = {};
#pragma unroll 1
  for (int kt = 0; kt < 16; ++kt) {
    // tile kt's 2 loads are oldest; keep tile kt+1's 2 in flight
    if (kt == 15) asm volatile("s_waitcnt vmcnt(0)" ::: "memory");
    else          asm volatile("s_waitcnt vmcnt(2)" ::: "memory");
    __builtin_amdgcn_s_barrier();
    __builtin_amdgcn_sched_barrier(0);
    bf16x8 af[2][2], bv[2][2];
#pragma unroll
    for (int fm = 0; fm < 2; ++fm)
#pragma unroll
      for (int ks = 0; ks < 2; ++ks)
        af[fm][ks] = *(const bf16x8*)(cA + aro[fm][ks]);
#pragma unroll
    for (int fn = 0; fn < 2; ++fn)
#pragma unroll
      for (int ks = 0; ks < 2; ++ks)
        bv[fn][ks] = *(const bf16x8*)(cB + bro[fn][ks]);
    asm volatile("s_waitcnt lgkmcnt(0)" ::: "memory");   // my reads done
    __builtin_amdgcn_s_barrier();                        // everyone's reads done
    __builtin_amdgcn_sched_barrier(0);
    if (kt < 14) {                  // stage tile kt+2 into the buffer just consumed
      int kofs = (kt + 2) * 32;
      gl_lds16(Wp + aoff + kofs, cA + ldso);
      gl_lds16(hTb + boff + kofs, cB + ldso);
    }
    __builtin_amdgcn_s_setprio(1);
#pragma unroll
    for (int ks = 0; ks < 2; ++ks)
#pragma unroll
      for (int fm = 0; fm < 2; ++fm)
#pragma unroll
        for (int fn = 0; fn < 2; ++fn)
          acc[fm][fn] = __builtin_amdgcn_mfma_f32_32x32x16_bf16(
              af[fm][ks], bv[fn][ks], acc[fm][fn], 0, 0, 0);
    __builtin_amdgcn_s_setprio(0);
    unsigned short* t1 = cA; cA = oA; oA = t1;
    unsigned short* t2 = cB; cB = oB; oB = t2;
  }

  // epilogue: out = rstd*acc + (s2[o]-mean*rstd*s1[o]) + x
  // 32x32 C layout: col=lane&31, row=(reg&3)+8*(reg>>2)+4*(lane>>5)
  float mean = wsf[32 + b], rstd = wsf[48 + b];
  float mr = mean * rstd;
#pragma unroll
  for (int fm = 0; fm < 2; ++fm) {
#pragma unroll
    for (int fn = 0; fn < 2; ++fn) {
      int t = nb * 256 + wn * 64 + fn * 32 + lr;
      if (t < T_) {
#pragma unroll
        for (int reg = 0; reg < 16; ++reg) {
          int o = mb * 256 + wm * 64 + fm * 32 + (reg & 3) + ((reg >> 2) << 3) + (lh << 2);
          float bias = wsf[576 + o] - mr * wsf[64 + o];
          size_t idx = ((size_t)b * C_ + o) * T_ + t;
          out[idx] = rstd * acc[fm][fn][reg] + bias + x[idx];
        }
      }
    }
  }
}

extern "C" void kernel_launch(void* const* d_in, const int* in_sizes, int n_in,
                              void* d_out, int out_size, void* d_ws, size_t ws_size,
                              hipStream_t stream) {
  const float* x   = (const float*)d_in[0];
  const float* bng = (const float*)d_in[1];
  const float* bnb = (const float*)d_in[2];
  const float* bnm = (const float*)d_in[3];
  const float* bnv = (const float*)d_in[4];
  const float* dw  = (const float*)d_in[5];
  const float* pa  = (const float*)d_in[6];
  const float* gg  = (const float*)d_in[7];
  const float* gb  = (const float*)d_in[8];
  const float* pw  = (const float*)d_in[9];
  float* out = (float*)d_out;
  float* wsf = (float*)d_ws;
  unsigned short* Wp = (unsigned short*)((char*)d_ws + 8192);
  unsigned short* hT = (unsigned short*)((char*)d_ws + (1 << 20));

  k_init<<<dim3(1), dim3(64), 0, stream>>>(wsf);
  k_prepw<<<dim3(512), dim3(64), 0, stream>>>(pw, gg, gb, Wp, wsf);
  k_front<<<dim3(16, 4, 16), dim3(512), 0, stream>>>(x, bng, bnb, bnm, bnv, dw, pa, hT, wsf);
  k_finalize<<<dim3(1), dim3(64), 0, stream>>>(wsf);
  k_gemm<<<dim3(16, 2, 16), dim3(1024), 0, stream>>>(Wp, hT, x, wsf, out);
}

// Round 9
// 192.952 us; speedup vs baseline: 6.8482x; 6.8482x over previous
//
#include <hip/hip_runtime.h>
#include <stdint.h>

// Problem constants
#define B_ 16
#define C_ 512
#define T_ 4000
#define TPAD 4096   // hT rows padded per batch

typedef float f32x4 __attribute__((ext_vector_type(4)));
typedef float f32x16 __attribute__((ext_vector_type(16)));
typedef __bf16 bf16x8 __attribute__((ext_vector_type(8)));

// ---------- helpers ----------
__device__ inline unsigned short f2b(float f) {   // fp32 -> bf16 bits, RNE
  uint32_t u = __builtin_bit_cast(uint32_t, f);
  u = (u + 0x7fffu + ((u >> 16) & 1u)) >> 16;
  return (unsigned short)u;
}
__device__ inline float b2f(unsigned short h) {
  uint32_t u = ((uint32_t)h) << 16;
  return __builtin_bit_cast(float, u);
}

// ws float layout: [0..15] sum, [16..31] sumsq, [32..47] mean, [48..63] rstd,
//                  [64..575] s1[o], [576..1087] s2[o]
// byte 8192  : Wp bf16 k-chunk-major: Wp[((c>>3)*512 + o)*8 + (c&7)]
// byte 1<<20 : hT bf16 [16][4096][512]  (t-major, c contiguous)

__global__ void k_init(float* wsf) {
  int i = threadIdx.x;
  if (i < 32) wsf[i] = 0.f;
}

// W'[o,c] = pw*gamma, k-chunk-major (validated R7); s1[o]=sum W', s2[o]=sum pw*beta
__global__ __launch_bounds__(64) void k_prepw(const float* __restrict__ pw,
                                              const float* __restrict__ gamma,
                                              const float* __restrict__ beta,
                                              unsigned short* __restrict__ Wp,
                                              float* __restrict__ wsf) {
  int o = blockIdx.x, l = threadIdx.x;
  float a1 = 0.f, a2 = 0.f;
  for (int j = 0; j < 8; ++j) {
    int c = j * 64 + l;
    float wv = pw[o * 512 + c];
    unsigned short wb = f2b(wv * gamma[c]);
    Wp[((size_t)(c >> 3) * 512 + o) * 8 + (c & 7)] = wb;
    a1 += b2f(wb);              // consistent with bf16 weights used in GEMM
    a2 += wv * beta[c];
  }
  for (int s = 32; s > 0; s >>= 1) { a1 += __shfl_down(a1, s); a2 += __shfl_down(a2, s); }
  if (l == 0) { wsf[64 + o] = a1; wsf[576 + o] = a2; }
}

// fused ReLU+BN+dwconv3+PReLU; writes hT[b][t][c] bf16 (transposed) + stats.
// (proven ~50us; unchanged since R2)
__global__ __launch_bounds__(512) void k_front(const float* __restrict__ x,
    const float* __restrict__ bng, const float* __restrict__ bnb,
    const float* __restrict__ bnm, const float* __restrict__ bnv,
    const float* __restrict__ dw, const float* __restrict__ pa,
    unsigned short* __restrict__ hT, float* __restrict__ wsf) {
  __shared__ unsigned short hs[256 * 128] __attribute__((aligned(16)));  // 64 KB
  __shared__ float psc[128], pbi[128], pq0[128], pq1[128], pq2[128];
  __shared__ float partial[16];
  int tid = threadIdx.x;
  int l = tid & 63, w = tid >> 6;
  int tb = blockIdx.x;   // 16 t-tiles of 256
  int cb = blockIdx.y;   // 4 c-chunks of 128
  int b  = blockIdx.z;
  int t0 = tb * 256;
  if (tid < 128) {
    int c = cb * 128 + tid;
    float sc = bng[c] * rsqrtf(bnv[c] + 1e-5f);
    psc[tid] = sc;
    pbi[tid] = bnb[c] - bnm[c] * sc;
    pq0[tid] = dw[3 * c];
    pq1[tid] = dw[3 * c + 1];
    pq2[tid] = dw[3 * c + 2];
  }
  float alpha = pa[0];
  __syncthreads();

  int t = t0 + 4 * l;
  bool full = (t + 3 < T_);
  bool has_l = (t0 > 0);
  bool has_r = (t0 + 256 < T_);
  float sum = 0.f, sq = 0.f;
  int cs_x = (l & 7) << 3;

#pragma unroll 2
  for (int i = 0; i < 16; ++i) {
    int cl = w * 16 + i;
    const float* xr = x + ((size_t)b * C_ + cb * 128 + cl) * T_;
    float sc = psc[cl], bi = pbi[cl];
    float w0 = pq0[cl], w1 = pq1[cl], w2 = pq2[cl];
    f32x4 u;
    if (full) {
      const f32x4 v = *(const f32x4*)(xr + t);
      u.x = fmaxf(v.x, 0.f) * sc + bi;
      u.y = fmaxf(v.y, 0.f) * sc + bi;
      u.z = fmaxf(v.z, 0.f) * sc + bi;
      u.w = fmaxf(v.w, 0.f) * sc + bi;
    } else {
      u = (f32x4){0.f, 0.f, 0.f, 0.f};
    }
    float el = has_l ? (fmaxf(xr[t0 - 1], 0.f) * sc + bi) : 0.f;
    float er = has_r ? (fmaxf(xr[t0 + 256], 0.f) * sc + bi) : 0.f;
    float up = __shfl_up(u.w, 1);   if (l == 0)  up = el;
    float un = __shfl_down(u.x, 1); if (l == 63) un = er;
    float h[4];
    h[0] = w0 * up  + w1 * u.x + w2 * u.y;
    h[1] = w0 * u.x + w1 * u.y + w2 * u.z;
    h[2] = w0 * u.y + w1 * u.z + w2 * u.w;
    h[3] = w0 * u.z + w1 * u.w + w2 * un;
    int cs = cl ^ cs_x;
#pragma unroll
    for (int j = 0; j < 4; ++j) {
      float p = h[j] >= 0.f ? h[j] : alpha * h[j];
      if (!full) p = 0.f;
      sum += p; sq += p * p;
      hs[(4 * l + j) * 128 + cs] = f2b(p);
    }
  }

  for (int s = 32; s > 0; s >>= 1) { sum += __shfl_down(sum, s); sq += __shfl_down(sq, s); }
  if (l == 0) { partial[w] = sum; partial[8 + w] = sq; }
  __syncthreads();
  if (tid == 0) {
    float a = 0.f, c2 = 0.f;
    for (int k = 0; k < 8; ++k) { a += partial[k]; c2 += partial[8 + k]; }
    atomicAdd(&wsf[b], a);
    atomicAdd(&wsf[16 + b], c2);
  }

  unsigned short* dstb = hT + ((size_t)b * TPAD + t0) * 512 + cb * 128;
#pragma unroll
  for (int p = 0; p < 8; ++p) {
    int idx = p * 512 + tid;
    int tl = idx >> 4, g = idx & 15;
    int gs = g ^ ((tl >> 2) & 7);
    uint4 val = *(const uint4*)(hs + tl * 128 + gs * 8);
    *(uint4*)(dstb + (size_t)tl * 512 + g * 8) = val;
  }
}

__global__ void k_finalize(float* wsf) {
  int b = threadIdx.x;
  if (b < 16) {
    float n = (float)C_ * (float)T_;
    float mean = wsf[b] / n;
    float var = wsf[16 + b] / n - mean * mean;
    wsf[32 + b] = mean;
    wsf[48 + b] = rsqrtf(fmaxf(var, 0.f) + 1e-8f);
  }
}

// GEMM v7: no LDS, no barriers, all-register operands, maximal wave independence.
// Grid = 125 t-tiles x 16 b = 2000 blocks, 512 thr = 8 independent waves.
// Wave w: 64o x 32t via mfma_32x32x16, acc 2xf32x16.
// A: k-major Wp, each load = two contiguous 512B runs (L2-hot, per-XCD once).
// B: hT rows t0..t0+31 (each element read by exactly one block; L1-shared by waves).
// Depth-1 register double-buffer, even/odd named bodies. No sync at all.
__global__ __launch_bounds__(512, 4) void k_gemm(const unsigned short* __restrict__ Wp,
    const unsigned short* __restrict__ hT, const float* __restrict__ x,
    const float* __restrict__ wsf, float* __restrict__ out) {
  int tid = threadIdx.x;
  int l = tid & 63, w = tid >> 6;
  int lr = l & 31, lh = l >> 5;
  int bid = blockIdx.x;
  int tt = bid % 125, b = bid / 125;
  int t0 = tt * 32;
  int o0 = w * 64;
  const unsigned short* hTb = hT + ((size_t)b * TPAD + t0) * 512;

  // per-lane element pointers
  const unsigned short* pA = Wp + ((size_t)lh * 512 + o0 + lr) * 8;  // + kt*8192 + fm*256
  const unsigned short* pB = hTb + lr * 512 + lh * 8;                // + kt*16

#define LDA(kt, fm) (*(const bf16x8*)(pA + (size_t)(kt) * 8192 + (fm) * 256))
#define LDB(kt)     (*(const bf16x8*)(pB + (kt) * 16))

  f32x16 acc0 = {}, acc1 = {};
  bf16x8 A00 = LDA(0, 0), A01 = LDA(0, 1), B0 = LDB(0);

#pragma unroll 1
  for (int kt = 0; kt < 32; kt += 2) {
    bf16x8 A10 = LDA(kt + 1, 0), A11 = LDA(kt + 1, 1), B1 = LDB(kt + 1);
    acc0 = __builtin_amdgcn_mfma_f32_32x32x16_bf16(A00, B0, acc0, 0, 0, 0);
    acc1 = __builtin_amdgcn_mfma_f32_32x32x16_bf16(A01, B0, acc1, 0, 0, 0);
    if (kt + 2 < 32) {
      A00 = LDA(kt + 2, 0); A01 = LDA(kt + 2, 1); B0 = LDB(kt + 2);
    }
    acc0 = __builtin_amdgcn_mfma_f32_32x32x16_bf16(A10, B1, acc0, 0, 0, 0);
    acc1 = __builtin_amdgcn_mfma_f32_32x32x16_bf16(A11, B1, acc1, 0, 0, 0);
  }
#undef LDA
#undef LDB

  // epilogue: out = rstd*acc + (s2[o]-mean*rstd*s1[o]) + x
  // 32x32 C layout: col(t)=lane&31, row(o)=(reg&3)+8*(reg>>2)+4*(lane>>5)
  float mean = wsf[32 + b], rstd = wsf[48 + b];
  float mr = mean * rstd;
  int t = t0 + lr;
#pragma unroll
  for (int fm = 0; fm < 2; ++fm) {
    const f32x16& a = fm ? acc1 : acc0;
#pragma unroll
    for (int reg = 0; reg < 16; ++reg) {
      int o = o0 + fm * 32 + (reg & 3) + ((reg >> 2) << 3) + (lh << 2);
      float bias = wsf[576 + o] - mr * wsf[64 + o];
      size_t idx = ((size_t)b * C_ + o) * T_ + t;
      out[idx] = rstd * a[reg] + bias + x[idx];
    }
  }
}

extern "C" void kernel_launch(void* const* d_in, const int* in_sizes, int n_in,
                              void* d_out, int out_size, void* d_ws, size_t ws_size,
                              hipStream_t stream) {
  const float* x   = (const float*)d_in[0];
  const float* bng = (const float*)d_in[1];
  const float* bnb = (const float*)d_in[2];
  const float* bnm = (const float*)d_in[3];
  const float* bnv = (const float*)d_in[4];
  const float* dw  = (const float*)d_in[5];
  const float* pa  = (const float*)d_in[6];
  const float* gg  = (const float*)d_in[7];
  const float* gb  = (const float*)d_in[8];
  const float* pw  = (const float*)d_in[9];
  float* out = (float*)d_out;
  float* wsf = (float*)d_ws;
  unsigned short* Wp = (unsigned short*)((char*)d_ws + 8192);
  unsigned short* hT = (unsigned short*)((char*)d_ws + (1 << 20));

  k_init<<<dim3(1), dim3(64), 0, stream>>>(wsf);
  k_prepw<<<dim3(512), dim3(64), 0, stream>>>(pw, gg, gb, Wp, wsf);
  k_front<<<dim3(16, 4, 16), dim3(512), 0, stream>>>(x, bng, bnb, bnm, bnv, dw, pa, hT, wsf);
  k_finalize<<<dim3(1), dim3(64), 0, stream>>>(wsf);
  k_gemm<<<dim3(2000), dim3(512), 0, stream>>>(Wp, hT, x, wsf, out);
}

// Round 11
// 153.468 us; speedup vs baseline: 8.6101x; 1.2573x over previous
//
#include <hip/hip_runtime.h>
#include <stdint.h>

// Problem constants
#define B_ 16
#define C_ 512
#define T_ 4000
#define TPAD 4096   // hT rows padded per batch so tail N-tiles read in-bounds

typedef float f32x4 __attribute__((ext_vector_type(4)));
typedef __bf16 bf16x8 __attribute__((ext_vector_type(8)));

// ---------- helpers ----------
__device__ inline unsigned short f2b(float f) {   // fp32 -> bf16 bits, RNE
  uint32_t u = __builtin_bit_cast(uint32_t, f);
  u = (u + 0x7fffu + ((u >> 16) & 1u)) >> 16;
  return (unsigned short)u;
}
__device__ inline float b2f(unsigned short h) {
  uint32_t u = ((uint32_t)h) << 16;
  return __builtin_bit_cast(float, u);
}
__device__ inline void gl_lds16(const void* g, void* s) {
  __builtin_amdgcn_global_load_lds(
      (const __attribute__((address_space(1))) uint32_t*)g,
      (__attribute__((address_space(3))) uint32_t*)s, 16, 0, 0);
}

// ws float layout: [0..15] sum, [16..31] sumsq, [32..47] mean, [48..63] rstd,
//                  [64..575] s1[o], [576..1087] s2[o]
// byte 8192  : Wp bf16 [512][512]  (pw * gln_gamma, row-major o,c)
// byte 1<<20 : hT bf16 [16][4096][512]  (t-major, c contiguous)

__global__ void k_init(float* wsf) {
  int i = threadIdx.x;
  if (i < 32) wsf[i] = 0.f;
}

// one block per output row o: W'[o,c] = pw*gamma (bf16), s1[o]=sum W', s2[o]=sum pw*beta
__global__ __launch_bounds__(64) void k_prepw(const float* __restrict__ pw,
                                              const float* __restrict__ gamma,
                                              const float* __restrict__ beta,
                                              unsigned short* __restrict__ Wp,
                                              float* __restrict__ wsf) {
  int o = blockIdx.x, l = threadIdx.x;
  float a1 = 0.f, a2 = 0.f;
  for (int j = 0; j < 8; ++j) {
    int c = j * 64 + l;
    float wv = pw[o * 512 + c];
    unsigned short wb = f2b(wv * gamma[c]);
    Wp[o * 512 + c] = wb;
    a1 += b2f(wb);              // consistent with bf16 weights used in GEMM
    a2 += wv * beta[c];
  }
  for (int s = 32; s > 0; s >>= 1) { a1 += __shfl_down(a1, s); a2 += __shfl_down(a2, s); }
  if (l == 0) { wsf[64 + o] = a1; wsf[576 + o] = a2; }
}

// fused ReLU+BN+dwconv3+PReLU; writes hT[b][t][c] bf16 (transposed) + stats.
// v2: c-chunk = 64 (LDS 32 KB) -> 4 blocks/CU for 2x TLP. Same indexing
// pattern as the proven 128-c version, shifted one bit down.
// Block: 512 thr = 8 waves. Tile: 256 t x 64 c. Lane l owns t = t0+4l..4l+3;
// wave w owns channels w*8 .. w*8+7.
__global__ __launch_bounds__(512) void k_front(const float* __restrict__ x,
    const float* __restrict__ bng, const float* __restrict__ bnb,
    const float* __restrict__ bnm, const float* __restrict__ bnv,
    const float* __restrict__ dw, const float* __restrict__ pa,
    unsigned short* __restrict__ hT, float* __restrict__ wsf) {
  __shared__ unsigned short hs[256 * 64] __attribute__((aligned(16)));  // 32 KB
  __shared__ float psc[64], pbi[64], pq0[64], pq1[64], pq2[64];
  __shared__ float partial[16];
  int tid = threadIdx.x;
  int l = tid & 63, w = tid >> 6;
  int tb = blockIdx.x;   // 16 t-tiles of 256
  int cb = blockIdx.y;   // 8 c-chunks of 64
  int b  = blockIdx.z;
  int t0 = tb * 256;
  if (tid < 64) {
    int c = cb * 64 + tid;
    float sc = bng[c] * rsqrtf(bnv[c] + 1e-5f);
    psc[tid] = sc;
    pbi[tid] = bnb[c] - bnm[c] * sc;
    pq0[tid] = dw[3 * c];
    pq1[tid] = dw[3 * c + 1];
    pq2[tid] = dw[3 * c + 2];
  }
  float alpha = pa[0];
  __syncthreads();

  int t = t0 + 4 * l;
  bool full = (t + 3 < T_);          // lanes are either fully valid or fully out
  bool has_l = (t0 > 0);
  bool has_r = (t0 + 256 < T_);
  float sum = 0.f, sq = 0.f;
  int cs_x = (l & 7) << 3;           // swizzle term

#pragma unroll 2
  for (int i = 0; i < 8; ++i) {
    int cl = w * 8 + i;
    const float* xr = x + ((size_t)b * C_ + cb * 64 + cl) * T_;
    float sc = psc[cl], bi = pbi[cl];
    float w0 = pq0[cl], w1 = pq1[cl], w2 = pq2[cl];
    f32x4 u;
    if (full) {
      const f32x4 v = *(const f32x4*)(xr + t);
      u.x = fmaxf(v.x, 0.f) * sc + bi;
      u.y = fmaxf(v.y, 0.f) * sc + bi;
      u.z = fmaxf(v.z, 0.f) * sc + bi;
      u.w = fmaxf(v.w, 0.f) * sc + bi;
    } else {
      u = (f32x4){0.f, 0.f, 0.f, 0.f};
    }
    float el = has_l ? (fmaxf(xr[t0 - 1], 0.f) * sc + bi) : 0.f;   // uniform addr
    float er = has_r ? (fmaxf(xr[t0 + 256], 0.f) * sc + bi) : 0.f; // uniform addr
    float up = __shfl_up(u.w, 1);   if (l == 0)  up = el;
    float un = __shfl_down(u.x, 1); if (l == 63) un = er;
    float h[4];
    h[0] = w0 * up  + w1 * u.x + w2 * u.y;
    h[1] = w0 * u.x + w1 * u.y + w2 * u.z;
    h[2] = w0 * u.y + w1 * u.z + w2 * u.w;
    h[3] = w0 * u.z + w1 * u.w + w2 * un;
    int cs = cl ^ cs_x;
#pragma unroll
    for (int j = 0; j < 4; ++j) {
      float p = h[j] >= 0.f ? h[j] : alpha * h[j];
      if (!full) p = 0.f;            // t >= 4000 rows stay exactly zero
      sum += p; sq += p * p;
      hs[(4 * l + j) * 64 + cs] = f2b(p);
    }
  }

  for (int s = 32; s > 0; s >>= 1) { sum += __shfl_down(sum, s); sq += __shfl_down(sq, s); }
  if (l == 0) { partial[w] = sum; partial[8 + w] = sq; }
  __syncthreads();
  if (tid == 0) {
    float a = 0.f, c2 = 0.f;
    for (int k = 0; k < 8; ++k) { a += partial[k]; c2 += partial[8 + k]; }
    atomicAdd(&wsf[b], a);
    atomicAdd(&wsf[16 + b], c2);
  }

  // LDS tile -> global hT[b][t0+tl][cb*64 + g*8], un-swizzled, 16B/thread/pass
  unsigned short* dstb = hT + ((size_t)b * TPAD + t0) * 512 + cb * 64;
#pragma unroll
  for (int p = 0; p < 4; ++p) {
    int idx = p * 512 + tid;
    int tl = idx >> 3, g = idx & 7;
    int gs = g ^ ((tl >> 2) & 7);
    uint4 val = *(const uint4*)(hs + tl * 64 + gs * 8);
    *(uint4*)(dstb + (size_t)tl * 512 + g * 8) = val;
  }
}

__global__ void k_finalize(float* wsf) {
  int b = threadIdx.x;
  if (b < 16) {
    float n = (float)C_ * (float)T_;
    float mean = wsf[b] / n;
    float var = wsf[16 + b] / n - mean * mean;
    wsf[32 + b] = mean;
    wsf[48 + b] = rsqrtf(fmaxf(var, 0.f) + 1e-8f);
  }
}

// GEMM (R3, proven 94us): counted-vmcnt depth-2 pipeline.
// 256x256 tile, BK=32, 8 waves (2M x 4N), double-buffered 64KB LDS.
// Per step kt: vmcnt(4) [tile kt landed, kt+1 stays in flight] -> barrier ->
// ds_read frags -> lgkmcnt(0) -> barrier -> stage tile kt+2 into same buffer ->
// MFMA cluster (setprio).
__global__ __launch_bounds__(512, 2) void k_gemm(const unsigned short* __restrict__ Wp,
    const unsigned short* __restrict__ hT, const float* __restrict__ x,
    const float* __restrict__ wsf, float* __restrict__ out) {
  __shared__ unsigned short As0[8192], As1[8192], Bs0[8192], Bs1[8192];  // 64 KB
  int tid = threadIdx.x;
  int l = tid & 63, w = tid >> 6;
  int nb = blockIdx.x, mb = blockIdx.y, b = blockIdx.z;
  int wm = w >> 2, wn = w & 3;       // 2 x 4 wave grid; per-wave 128 o x 64 t
  const unsigned short* hTb = hT + (size_t)b * TPAD * 512;

  // staging source offsets (element units), inverse-swizzled k-slot
  int aoff[2], boff[2], ldso[2];
#pragma unroll
  for (int r = 0; r < 2; ++r) {
    int i = r * 512 + tid;           // 16B-unit index, 0..1023 (256 rows x 4 slots)
    int row = i >> 2, s = i & 3;
    int ksl = (s ^ ((row >> 1) & 3)) << 3;
    aoff[r] = (mb * 256 + row) * 512 + ksl;
    boff[r] = (nb * 256 + row) * 512 + ksl;
    ldso[r] = i * 8;                 // element offset in LDS panel
  }

  // ds_read fragment offsets (element units)
  int aro[8], bro[4];
#pragma unroll
  for (int fm = 0; fm < 8; ++fm) {
    int row = wm * 128 + fm * 16 + (l & 15);
    int slot = (l >> 4) ^ ((row >> 1) & 3);
    aro[fm] = row * 32 + slot * 8;
  }
#pragma unroll
  for (int fn = 0; fn < 4; ++fn) {
    int row = wn * 64 + fn * 16 + (l & 15);
    int slot = (l >> 4) ^ ((row >> 1) & 3);
    bro[fn] = row * 32 + slot * 8;
  }

  // prologue: stage K-tile 0 -> buf0, K-tile 1 -> buf1; no drain here
#pragma unroll
  for (int r = 0; r < 2; ++r) {
    gl_lds16(Wp + aoff[r], As0 + ldso[r]);
    gl_lds16(hTb + boff[r], Bs0 + ldso[r]);
  }
#pragma unroll
  for (int r = 0; r < 2; ++r) {
    gl_lds16(Wp + aoff[r] + 32, As1 + ldso[r]);
    gl_lds16(hTb + boff[r] + 32, Bs1 + ldso[r]);
  }

  unsigned short *cA = As0, *cB = Bs0;   // current (read + restage) buffers
  unsigned short *oA = As1, *oB = Bs1;   // other pair

  f32x4 acc[8][4] = {};
#pragma unroll 1
  for (int kt = 0; kt < 16; ++kt) {
    // tile kt's loads are the oldest; keep tile kt+1's 4 loads in flight
    if (kt == 15) asm volatile("s_waitcnt vmcnt(0)" ::: "memory");
    else          asm volatile("s_waitcnt vmcnt(4)" ::: "memory");
    __builtin_amdgcn_s_barrier();
    __builtin_amdgcn_sched_barrier(0);
    bf16x8 af[8], bv[4];
#pragma unroll
    for (int fm = 0; fm < 8; ++fm) af[fm] = *(const bf16x8*)(cA + aro[fm]);
#pragma unroll
    for (int fn = 0; fn < 4; ++fn) bv[fn] = *(const bf16x8*)(cB + bro[fn]);
    asm volatile("s_waitcnt lgkmcnt(0)" ::: "memory");   // my reads of cur buf done
    __builtin_amdgcn_s_barrier();                        // everyone's reads done
    __builtin_amdgcn_sched_barrier(0);
    if (kt < 14) {                  // stage tile kt+2 into the buffer just consumed
      int kofs = (kt + 2) * 32;
#pragma unroll
      for (int r = 0; r < 2; ++r) {
        gl_lds16(Wp + aoff[r] + kofs, cA + ldso[r]);
        gl_lds16(hTb + boff[r] + kofs, cB + ldso[r]);
      }
    }
    __builtin_amdgcn_s_setprio(1);
#pragma unroll
    for (int fm = 0; fm < 8; ++fm)
#pragma unroll
      for (int fn = 0; fn < 4; ++fn)
        acc[fm][fn] = __builtin_amdgcn_mfma_f32_16x16x32_bf16(af[fm], bv[fn], acc[fm][fn], 0, 0, 0);
    __builtin_amdgcn_s_setprio(0);
    unsigned short* t1 = cA; cA = oA; oA = t1;
    unsigned short* t2 = cB; cB = oB; oB = t2;
  }

  float mean = wsf[32 + b], rstd = wsf[48 + b];
  float mr = mean * rstd;
#pragma unroll
  for (int fm = 0; fm < 8; ++fm) {
    int o0 = mb * 256 + wm * 128 + fm * 16 + ((l >> 4) << 2);
    float bias[4];
#pragma unroll
    for (int j = 0; j < 4; ++j) {
      int o = o0 + j;
      bias[j] = wsf[576 + o] - mr * wsf[64 + o];
    }
#pragma unroll
    for (int fn = 0; fn < 4; ++fn) {
      int t = nb * 256 + wn * 64 + fn * 16 + (l & 15);
      if (t < T_) {
#pragma unroll
        for (int j = 0; j < 4; ++j) {
          int o = o0 + j;
          size_t idx = ((size_t)b * C_ + o) * T_ + t;
          out[idx] = rstd * acc[fm][fn][j] + bias[j] + x[idx];
        }
      }
    }
  }
}

extern "C" void kernel_launch(void* const* d_in, const int* in_sizes, int n_in,
                              void* d_out, int out_size, void* d_ws, size_t ws_size,
                              hipStream_t stream) {
  const float* x   = (const float*)d_in[0];
  const float* bng = (const float*)d_in[1];
  const float* bnb = (const float*)d_in[2];
  const float* bnm = (const float*)d_in[3];
  const float* bnv = (const float*)d_in[4];
  const float* dw  = (const float*)d_in[5];
  const float* pa  = (const float*)d_in[6];
  const float* gg  = (const float*)d_in[7];
  const float* gb  = (const float*)d_in[8];
  const float* pw  = (const float*)d_in[9];
  float* out = (float*)d_out;
  float* wsf = (float*)d_ws;
  unsigned short* Wp = (unsigned short*)((char*)d_ws + 8192);
  unsigned short* hT = (unsigned short*)((char*)d_ws + (1 << 20));

  k_init<<<dim3(1), dim3(64), 0, stream>>>(wsf);
  k_prepw<<<dim3(512), dim3(64), 0, stream>>>(pw, gg, gb, Wp, wsf);
  k_front<<<dim3(16, 8, 16), dim3(512), 0, stream>>>(x, bng, bnb, bnm, bnv, dw, pa, hT, wsf);
  k_finalize<<<dim3(1), dim3(64), 0, stream>>>(wsf);
  k_gemm<<<dim3(16, 2, 16), dim3(512), 0, stream>>>(Wp, hT, x, wsf, out);
}

// Round 12
// 153.041 us; speedup vs baseline: 8.6341x; 1.0028x over previous
//
#include <hip/hip_runtime.h>
#include <stdint.h>

// Problem constants
#define B_ 16
#define C_ 512
#define T_ 4000
#define TPAD 4096   // hT rows padded per batch so tail N-tiles read in-bounds

typedef float f32x4 __attribute__((ext_vector_type(4)));
typedef __bf16 bf16x8 __attribute__((ext_vector_type(8)));

// ---------- helpers ----------
__device__ inline unsigned short f2b(float f) {   // fp32 -> bf16 bits, RNE
  uint32_t u = __builtin_bit_cast(uint32_t, f);
  u = (u + 0x7fffu + ((u >> 16) & 1u)) >> 16;
  return (unsigned short)u;
}
__device__ inline float b2f(unsigned short h) {
  uint32_t u = ((uint32_t)h) << 16;
  return __builtin_bit_cast(float, u);
}
__device__ inline void gl_lds16(const void* g, void* s) {
  __builtin_amdgcn_global_load_lds(
      (const __attribute__((address_space(1))) uint32_t*)g,
      (__attribute__((address_space(3))) uint32_t*)s, 16, 0, 0);
}

// ws float layout: [0..15] sum, [16..31] sumsq, [64..575] s1[o], [576..1087] s2[o]
// byte 8192  : Wp bf16 [512][512]  (pw * gln_gamma, row-major o,c)
// byte 1<<20 : hT bf16 [16][4096][512]  (t-major, c contiguous)

// one block per output row o: W'[o,c] = pw*gamma (bf16), s1[o]=sum W', s2[o]=sum pw*beta
// block 0 additionally zeroes the stats accumulators (replaces k_init).
__global__ __launch_bounds__(64) void k_prepw(const float* __restrict__ pw,
                                              const float* __restrict__ gamma,
                                              const float* __restrict__ beta,
                                              unsigned short* __restrict__ Wp,
                                              float* __restrict__ wsf) {
  int o = blockIdx.x, l = threadIdx.x;
  if (o == 0 && l < 32) wsf[l] = 0.f;
  float a1 = 0.f, a2 = 0.f;
  for (int j = 0; j < 8; ++j) {
    int c = j * 64 + l;
    float wv = pw[o * 512 + c];
    unsigned short wb = f2b(wv * gamma[c]);
    Wp[o * 512 + c] = wb;
    a1 += b2f(wb);              // consistent with bf16 weights used in GEMM
    a2 += wv * beta[c];
  }
  for (int s = 32; s > 0; s >>= 1) { a1 += __shfl_down(a1, s); a2 += __shfl_down(a2, s); }
  if (l == 0) { wsf[64 + o] = a1; wsf[576 + o] = a2; }
}

// fused ReLU+BN+dwconv3+PReLU; writes hT[b][t][c] bf16 (transposed) + stats.
// v3: all 24 global loads issued UP FRONT (T14 async-issue) so HBM latency
// overlaps; compute phase identical to the proven version.
// Block: 512 thr = 8 waves. Tile: 256 t x 64 c. Lane l owns t = t0+4l..4l+3;
// wave w owns channels w*8 .. w*8+7. LDS 32 KB.
__global__ __launch_bounds__(512) void k_front(const float* __restrict__ x,
    const float* __restrict__ bng, const float* __restrict__ bnb,
    const float* __restrict__ bnm, const float* __restrict__ bnv,
    const float* __restrict__ dw, const float* __restrict__ pa,
    unsigned short* __restrict__ hT, float* __restrict__ wsf) {
  __shared__ unsigned short hs[256 * 64] __attribute__((aligned(16)));  // 32 KB
  __shared__ float psc[64], pbi[64], pq0[64], pq1[64], pq2[64];
  __shared__ float partial[16];
  int tid = threadIdx.x;
  int l = tid & 63, w = tid >> 6;
  int tb = blockIdx.x;   // 16 t-tiles of 256
  int cb = blockIdx.y;   // 8 c-chunks of 64
  int b  = blockIdx.z;
  int t0 = tb * 256;
  if (tid < 64) {
    int c = cb * 64 + tid;
    float sc = bng[c] * rsqrtf(bnv[c] + 1e-5f);
    psc[tid] = sc;
    pbi[tid] = bnb[c] - bnm[c] * sc;
    pq0[tid] = dw[3 * c];
    pq1[tid] = dw[3 * c + 1];
    pq2[tid] = dw[3 * c + 2];
  }
  float alpha = pa[0];
  __syncthreads();

  int t = t0 + 4 * l;
  bool full = (t + 3 < T_);          // lanes are either fully valid or fully out
  bool has_l = (t0 > 0);
  bool has_r = (t0 + 256 < T_);

  // ---- issue ALL global loads up front (24 VMEM in flight per lane) ----
  f32x4 xv[8];
  float xel[8], xer[8];
#pragma unroll
  for (int i = 0; i < 8; ++i) {
    const float* xr = x + ((size_t)b * C_ + cb * 64 + w * 8 + i) * T_;
    if (full) xv[i] = *(const f32x4*)(xr + t);
    else      xv[i] = (f32x4){0.f, 0.f, 0.f, 0.f};
    xel[i] = has_l ? xr[t0 - 1] : 0.f;     // uniform addr
    xer[i] = has_r ? xr[t0 + 256] : 0.f;   // uniform addr
  }

  // ---- compute phase (identical arithmetic to proven version) ----
  float sum = 0.f, sq = 0.f;
  int cs_x = (l & 7) << 3;           // swizzle term
#pragma unroll
  for (int i = 0; i < 8; ++i) {
    int cl = w * 8 + i;
    float sc = psc[cl], bi = pbi[cl];
    float w0 = pq0[cl], w1 = pq1[cl], w2 = pq2[cl];
    f32x4 u;
    if (full) {
      u.x = fmaxf(xv[i].x, 0.f) * sc + bi;
      u.y = fmaxf(xv[i].y, 0.f) * sc + bi;
      u.z = fmaxf(xv[i].z, 0.f) * sc + bi;
      u.w = fmaxf(xv[i].w, 0.f) * sc + bi;
    } else {
      u = (f32x4){0.f, 0.f, 0.f, 0.f};
    }
    float el = has_l ? (fmaxf(xel[i], 0.f) * sc + bi) : 0.f;
    float er = has_r ? (fmaxf(xer[i], 0.f) * sc + bi) : 0.f;
    float up = __shfl_up(u.w, 1);   if (l == 0)  up = el;
    float un = __shfl_down(u.x, 1); if (l == 63) un = er;
    float h[4];
    h[0] = w0 * up  + w1 * u.x + w2 * u.y;
    h[1] = w0 * u.x + w1 * u.y + w2 * u.z;
    h[2] = w0 * u.y + w1 * u.z + w2 * u.w;
    h[3] = w0 * u.z + w1 * u.w + w2 * un;
    int cs = cl ^ cs_x;
#pragma unroll
    for (int j = 0; j < 4; ++j) {
      float p = h[j] >= 0.f ? h[j] : alpha * h[j];
      if (!full) p = 0.f;            // t >= 4000 rows stay exactly zero
      sum += p; sq += p * p;
      hs[(4 * l + j) * 64 + cs] = f2b(p);
    }
  }

  for (int s = 32; s > 0; s >>= 1) { sum += __shfl_down(sum, s); sq += __shfl_down(sq, s); }
  if (l == 0) { partial[w] = sum; partial[8 + w] = sq; }
  __syncthreads();
  if (tid == 0) {
    float a = 0.f, c2 = 0.f;
    for (int k = 0; k < 8; ++k) { a += partial[k]; c2 += partial[8 + k]; }
    atomicAdd(&wsf[b], a);
    atomicAdd(&wsf[16 + b], c2);
  }

  // LDS tile -> global hT[b][t0+tl][cb*64 + g*8], un-swizzled, 16B/thread/pass
  unsigned short* dstb = hT + ((size_t)b * TPAD + t0) * 512 + cb * 64;
#pragma unroll
  for (int p = 0; p < 4; ++p) {
    int idx = p * 512 + tid;
    int tl = idx >> 3, g = idx & 7;
    int gs = g ^ ((tl >> 2) & 7);
    uint4 val = *(const uint4*)(hs + tl * 64 + gs * 8);
    *(uint4*)(dstb + (size_t)tl * 512 + g * 8) = val;
  }
}

// GEMM (R3, proven 94-95us): counted-vmcnt depth-2 pipeline.
// 256x256 tile, BK=32, 8 waves (2M x 4N), double-buffered 64KB LDS.
// Stats finalize folded in (replaces k_finalize): each block recomputes
// mean/rstd from the summed wsf[b], wsf[16+b] (deterministic).
__global__ __launch_bounds__(512, 2) void k_gemm(const unsigned short* __restrict__ Wp,
    const unsigned short* __restrict__ hT, const float* __restrict__ x,
    const float* __restrict__ wsf, float* __restrict__ out) {
  __shared__ unsigned short As0[8192], As1[8192], Bs0[8192], Bs1[8192];  // 64 KB
  int tid = threadIdx.x;
  int l = tid & 63, w = tid >> 6;
  int nb = blockIdx.x, mb = blockIdx.y, b = blockIdx.z;
  int wm = w >> 2, wn = w & 3;       // 2 x 4 wave grid; per-wave 128 o x 64 t
  const unsigned short* hTb = hT + (size_t)b * TPAD * 512;

  // staging source offsets (element units), inverse-swizzled k-slot
  int aoff[2], boff[2], ldso[2];
#pragma unroll
  for (int r = 0; r < 2; ++r) {
    int i = r * 512 + tid;           // 16B-unit index, 0..1023 (256 rows x 4 slots)
    int row = i >> 2, s = i & 3;
    int ksl = (s ^ ((row >> 1) & 3)) << 3;
    aoff[r] = (mb * 256 + row) * 512 + ksl;
    boff[r] = (nb * 256 + row) * 512 + ksl;
    ldso[r] = i * 8;                 // element offset in LDS panel
  }

  // ds_read fragment offsets (element units)
  int aro[8], bro[4];
#pragma unroll
  for (int fm = 0; fm < 8; ++fm) {
    int row = wm * 128 + fm * 16 + (l & 15);
    int slot = (l >> 4) ^ ((row >> 1) & 3);
    aro[fm] = row * 32 + slot * 8;
  }
#pragma unroll
  for (int fn = 0; fn < 4; ++fn) {
    int row = wn * 64 + fn * 16 + (l & 15);
    int slot = (l >> 4) ^ ((row >> 1) & 3);
    bro[fn] = row * 32 + slot * 8;
  }

  // prologue: stage K-tile 0 -> buf0, K-tile 1 -> buf1; no drain here
#pragma unroll
  for (int r = 0; r < 2; ++r) {
    gl_lds16(Wp + aoff[r], As0 + ldso[r]);
    gl_lds16(hTb + boff[r], Bs0 + ldso[r]);
  }
#pragma unroll
  for (int r = 0; r < 2; ++r) {
    gl_lds16(Wp + aoff[r] + 32, As1 + ldso[r]);
    gl_lds16(hTb + boff[r] + 32, Bs1 + ldso[r]);
  }

  unsigned short *cA = As0, *cB = Bs0;   // current (read + restage) buffers
  unsigned short *oA = As1, *oB = Bs1;   // other pair

  f32x4 acc[8][4] = {};
#pragma unroll 1
  for (int kt = 0; kt < 16; ++kt) {
    // tile kt's loads are the oldest; keep tile kt+1's 4 loads in flight
    if (kt == 15) asm volatile("s_waitcnt vmcnt(0)" ::: "memory");
    else          asm volatile("s_waitcnt vmcnt(4)" ::: "memory");
    __builtin_amdgcn_s_barrier();
    __builtin_amdgcn_sched_barrier(0);
    bf16x8 af[8], bv[4];
#pragma unroll
    for (int fm = 0; fm < 8; ++fm) af[fm] = *(const bf16x8*)(cA + aro[fm]);
#pragma unroll
    for (int fn = 0; fn < 4; ++fn) bv[fn] = *(const bf16x8*)(cB + bro[fn]);
    asm volatile("s_waitcnt lgkmcnt(0)" ::: "memory");   // my reads of cur buf done
    __builtin_amdgcn_s_barrier();                        // everyone's reads done
    __builtin_amdgcn_sched_barrier(0);
    if (kt < 14) {                  // stage tile kt+2 into the buffer just consumed
      int kofs = (kt + 2) * 32;
#pragma unroll
      for (int r = 0; r < 2; ++r) {
        gl_lds16(Wp + aoff[r] + kofs, cA + ldso[r]);
        gl_lds16(hTb + boff[r] + kofs, cB + ldso[r]);
      }
    }
    __builtin_amdgcn_s_setprio(1);
#pragma unroll
    for (int fm = 0; fm < 8; ++fm)
#pragma unroll
      for (int fn = 0; fn < 4; ++fn)
        acc[fm][fn] = __builtin_amdgcn_mfma_f32_16x16x32_bf16(af[fm], bv[fn], acc[fm][fn], 0, 0, 0);
    __builtin_amdgcn_s_setprio(0);
    unsigned short* t1 = cA; cA = oA; oA = t1;
    unsigned short* t2 = cB; cB = oB; oB = t2;
  }

  // finalize stats locally (replaces k_finalize; deterministic across blocks)
  float n = (float)C_ * (float)T_;
  float mean = wsf[b] / n;
  float var = wsf[16 + b] / n - mean * mean;
  float rstd = rsqrtf(fmaxf(var, 0.f) + 1e-8f);
  float mr = mean * rstd;
#pragma unroll
  for (int fm = 0; fm < 8; ++fm) {
    int o0 = mb * 256 + wm * 128 + fm * 16 + ((l >> 4) << 2);
    float bias[4];
#pragma unroll
    for (int j = 0; j < 4; ++j) {
      int o = o0 + j;
      bias[j] = wsf[576 + o] - mr * wsf[64 + o];
    }
#pragma unroll
    for (int fn = 0; fn < 4; ++fn) {
      int t = nb * 256 + wn * 64 + fn * 16 + (l & 15);
      if (t < T_) {
#pragma unroll
        for (int j = 0; j < 4; ++j) {
          int o = o0 + j;
          size_t idx = ((size_t)b * C_ + o) * T_ + t;
          out[idx] = rstd * acc[fm][fn][j] + bias[j] + x[idx];
        }
      }
    }
  }
}

extern "C" void kernel_launch(void* const* d_in, const int* in_sizes, int n_in,
                              void* d_out, int out_size, void* d_ws, size_t ws_size,
                              hipStream_t stream) {
  const float* x   = (const float*)d_in[0];
  const float* bng = (const float*)d_in[1];
  const float* bnb = (const float*)d_in[2];
  const float* bnm = (const float*)d_in[3];
  const float* bnv = (const float*)d_in[4];
  const float* dw  = (const float*)d_in[5];
  const float* pa  = (const float*)d_in[6];
  const float* gg  = (const float*)d_in[7];
  const float* gb  = (const float*)d_in[8];
  const float* pw  = (const float*)d_in[9];
  float* out = (float*)d_out;
  float* wsf = (float*)d_ws;
  unsigned short* Wp = (unsigned short*)((char*)d_ws + 8192);
  unsigned short* hT = (unsigned short*)((char*)d_ws + (1 << 20));

  k_prepw<<<dim3(512), dim3(64), 0, stream>>>(pw, gg, gb, Wp, wsf);
  k_front<<<dim3(16, 8, 16), dim3(512), 0, stream>>>(x, bng, bnb, bnm, bnv, dw, pa, hT, wsf);
  k_gemm<<<dim3(16, 2, 16), dim3(512), 0, stream>>>(Wp, hT, x, wsf, out);
}